// Round 2
// 625.819 us; speedup vs baseline: 1.0257x; 1.0257x over previous
//
#include <hip/hip_runtime.h>

// out[b,j,p] = sum_d x[b, nfj[j], d] * W[j,p,d] + bias[j,p]
// B=16384, N=32, D=256, J=23, P=2.
// Memory-bound: ~386 MB x-read floor (~62 us @ 6.3 TB/s).
//
// j is a block coordinate (blockIdx.y). W[j] lives in 32 VGPRs per lane
// (loaded once), nfj/bias are one-time scalar loads, and each wave streams
// 64 b-rows so the prologue is amortized ~16x. Steady-state per 1KB row:
// 1 nontemporal global_load + 8 FMA + 2 shfl — no W traffic at all.

constexpr int Bn = 16384;
constexpr int Nn = 32;
constexpr int Dn = 256;
constexpr int Jn = 23;
constexpr int Pn = 2;

constexpr int ROWS_PER_BLOCK = 256;                      // b-strip per block
constexpr int WAVES_PER_BLOCK = 4;                       // 256 threads
constexpr int ROWS_PER_WAVE = ROWS_PER_BLOCK / WAVES_PER_BLOCK;  // 64

// clang-native vector type: __builtin_nontemporal_load needs this,
// HIP_vector_type<float,4> is rejected.
typedef float floatx4 __attribute__((ext_vector_type(4)));

__global__ __launch_bounds__(256) void detok_kernel(
    const float* __restrict__ x, const float* __restrict__ W,
    const float* __restrict__ bias, const int* __restrict__ nfj,
    float* __restrict__ out)
{
    const int j     = blockIdx.y;           // 0..22 (uniform per block)
    const int strip = blockIdx.x;           // 0..63
    const int wave  = threadIdx.x >> 6;     // 0..3
    const int lane  = threadIdx.x & 63;
    const int group = lane >> 4;            // 0..3: which row of the 4-row step
    const int gl    = lane & 15;            // lane within group

    const int node = nfj[j];                // uniform -> s_load

    // Hoist W[j,0,:], W[j,1,:] fragments into registers.
    // Lane gl owns float4 indices {gl, 16+gl, 32+gl, 48+gl} of the 256-float row.
    const floatx4* __restrict__ w0p =
        reinterpret_cast<const floatx4*>(W + ((size_t)j * Pn + 0) * Dn);
    const floatx4* __restrict__ w1p =
        reinterpret_cast<const floatx4*>(W + ((size_t)j * Pn + 1) * Dn);
    floatx4 w0[4], w1[4];
#pragma unroll
    for (int k = 0; k < 4; ++k) {
        w0[k] = w0p[k * 16 + gl];
        w1[k] = w1p[k * 16 + gl];
    }

    const float2 bj = *reinterpret_cast<const float2*>(bias + j * Pn);  // uniform

    // This wave's 64 rows, processed 4 at a time (one per 16-lane group).
    const int b0 = strip * ROWS_PER_BLOCK + wave * ROWS_PER_WAVE;

#pragma unroll 2
    for (int it = 0; it < ROWS_PER_WAVE; it += 4) {
        const int b = b0 + it + group;
        const floatx4* __restrict__ xr = reinterpret_cast<const floatx4*>(
            x + ((size_t)b * Nn + node) * Dn);

        float s0 = 0.f, s1 = 0.f;
#pragma unroll
        for (int k = 0; k < 4; ++k) {
            floatx4 xv = __builtin_nontemporal_load(&xr[k * 16 + gl]);
            s0 += xv.x * w0[k].x + xv.y * w0[k].y + xv.z * w0[k].z + xv.w * w0[k].w;
            s1 += xv.x * w1[k].x + xv.y * w1[k].y + xv.z * w1[k].z + xv.w * w1[k].w;
        }

        // reduce across the 16-lane group (xor masks 1..8 stay inside the group)
#pragma unroll
        for (int off = 8; off >= 1; off >>= 1) {
            s0 += __shfl_xor(s0, off, 16);
            s1 += __shfl_xor(s1, off, 16);
        }

        if (gl == 0) {
            float2 o;
            o.x = s0 + bj.x;
            o.y = s1 + bj.y;
            *reinterpret_cast<float2*>(out + ((size_t)b * Jn + j) * Pn) = o;
        }
    }
}

extern "C" void kernel_launch(void* const* d_in, const int* in_sizes, int n_in,
                              void* d_out, int out_size, void* d_ws, size_t ws_size,
                              hipStream_t stream) {
    const float* x    = (const float*)d_in[0];
    const float* W    = (const float*)d_in[1];
    const float* bias = (const float*)d_in[2];
    const int*   nfj  = (const int*)d_in[3];
    float* out = (float*)d_out;

    dim3 grid(Bn / ROWS_PER_BLOCK, Jn);   // (64, 23) — exact, no tails
    detok_kernel<<<grid, 256, 0, stream>>>(x, W, bias, nfj, out);
}